// Round 1
// baseline (2086.103 us; speedup 1.0000x reference)
//
#include <hip/hip_runtime.h>
#include <math.h>

// FermiNet Ansatz_fb forward, fully fused: 1 block (256 thr) per walker.
// State in LDS; weights streamed from global (L2-resident).
// svT[j*20+e] = s_v[e][j] (feature-major, rows of 20 floats = 80B, 16B-aligned)
// pvbuf[i][j][c] = p_v; later reused for suT/sdT/orb.

namespace {

constexpr float SQRT3 = 1.7320508075688772f;

__global__ __launch_bounds__(256, 2) void ansatz_fused(
    const float* __restrict__ r,     // [B,20,3]
    const float* __restrict__ a_g,   // [4,3]
    const float* __restrict__ s_w0,  // [56,256]
    const float* __restrict__ s_b0,  // [256]
    const float* __restrict__ s_w,   // [3,832,256]
    const float* __restrict__ s_b,   // [3,256]
    const float* __restrict__ p_w0,  // [4,32]
    const float* __restrict__ p_b0,  // [32]
    const float* __restrict__ p_w,   // [3,32,32]
    const float* __restrict__ p_b,   // [3,32]
    const float* __restrict__ vu_w, const float* __restrict__ vu_b,
    const float* __restrict__ vd_w, const float* __restrict__ vd_b,
    const float* __restrict__ wu_w, const float* __restrict__ wu_b,
    const float* __restrict__ wd_w, const float* __restrict__ wd_b,
    const float* __restrict__ wf_w,  // [16]
    float* __restrict__ out)         // [B]
{
  const int b = blockIdx.x;
  const int tid = threadIdx.x;

  __shared__ float svT[256 * 20];        // 20480 B
  __shared__ float pvbuf[20 * 20 * 32];  // 51200 B (reused: suT/sdT/orb)
  __shared__ float mu[256], md[256];     // single-stream means
  __shared__ float puT[32 * 20], pdT[32 * 20];  // pair means, [c][j]
  __shared__ float sinT[16 * 20];        // s-input features, [k][e]
  __shared__ float rl[20][3];
  __shared__ float apos[4][3];
  __shared__ float expv[20];             // exp envelope sums per electron
  __shared__ float lu_s[32], sg_s[32];

  // ---- geometry load ----
  if (tid < 60) (&rl[0][0])[tid] = r[b * 60 + tid];
  if (tid >= 64 && tid < 76) (&apos[0][0])[tid - 64] = a_g[tid - 64];
  __syncthreads();

  // s-input features sinT[k][e]: k = atom*4 + {dx,dy,dz,len}
  for (int t = tid; t < 320; t += 256) {
    int k = t / 20, e = t % 20;
    int at = k >> 2, comp = k & 3;
    float dx = rl[e][0] - apos[at][0];
    float dy = rl[e][1] - apos[at][1];
    float dz = rl[e][2] - apos[at][2];
    float v;
    if (comp == 0) v = dx;
    else if (comp == 1) v = dy;
    else if (comp == 2) v = dz;
    else v = sqrtf(dx * dx + dy * dy + dz * dz);
    sinT[k * 20 + e] = v;
  }
  // layer-0 pair means (c<4) directly from geometry: puT[c*20+j]
  for (int t = tid; t < 160; t += 256) {
    int half = t / 80, rem = t % 80, c = rem / 20, j = rem % 20;
    float s = 0.f;
    for (int i = half * 10; i < half * 10 + 10; ++i) {
      if (c < 3) {
        s += rl[j][c] - rl[i][c];
      } else if (i == j) {
        s += SQRT3;  // ||(1,1,1)|| from the eye trick
      } else {
        float dx = rl[j][0] - rl[i][0], dy = rl[j][1] - rl[i][1], dz = rl[j][2] - rl[i][2];
        s += sqrtf(dx * dx + dy * dy + dz * dz);
      }
    }
    (half ? pdT : puT)[c * 20 + j] = s * 0.1f;
  }
  __syncthreads();

  // exp envelopes + layer-0 s means (k<16)
  if (tid < 20) {
    float s = 0.f;
    for (int at = 0; at < 4; ++at) s += expf(-sinT[(at * 4 + 3) * 20 + tid]);
    expv[tid] = s;
  }
  if (tid < 32) {
    int k = tid & 15, half = tid >> 4;
    float s = 0.f;
    for (int e = half * 10; e < half * 10 + 10; ++e) s += sinT[k * 20 + e];
    (half ? md : mu)[k] = s * 0.1f;
  }
  __syncthreads();

  // ---- layer 0, single stream (no residual) ----
  {
    const int j = tid;
    float accm = s_b0[j];
#pragma unroll
    for (int k = 0; k < 16; ++k)
      accm += mu[k] * s_w0[(16 + k) * 256 + j] + md[k] * s_w0[(32 + k) * 256 + j];
    float sv0[20];
#pragma unroll
    for (int e = 0; e < 20; ++e) {
      float acc = accm;
#pragma unroll
      for (int k = 0; k < 16; ++k) acc += sinT[k * 20 + e] * s_w0[k * 256 + j];
#pragma unroll
      for (int c = 0; c < 4; ++c)
        acc += puT[c * 20 + e] * s_w0[(48 + c) * 256 + j] +
               pdT[c * 20 + e] * s_w0[(52 + c) * 256 + j];
      sv0[e] = tanhf(acc);
    }
#pragma unroll
    for (int e = 0; e < 20; ++e) svT[j * 20 + e] = sv0[e];
  }
  // ---- layer 0, pair stream (no residual) ----
  {
    const int c = tid & 31;  // output channel is constant per thread
    float pw0c[4];
#pragma unroll
    for (int k = 0; k < 4; ++k) pw0c[k] = p_w0[k * 32 + c];
    const float pb0c = p_b0[c];
    for (int s = 0; s < 50; ++s) {
      int o = tid + 256 * s;
      int i = o / 640, rem = o % 640, j = rem >> 5;
      float dx = rl[j][0] - rl[i][0], dy = rl[j][1] - rl[i][1], dz = rl[j][2] - rl[i][2];
      float len = (i == j) ? SQRT3 : sqrtf(dx * dx + dy * dy + dz * dz);
      pvbuf[o] = tanhf(pb0c + dx * pw0c[0] + dy * pw0c[1] + dz * pw0c[2] + len * pw0c[3]);
    }
  }
  __syncthreads();

  // ---- residual layers (l=0..2) + final means pass (l=3) ----
  for (int l = 0; l < 4; ++l) {
    // means from current svT / pvbuf
    {
      const int k = tid;
      float su_ = 0.f, sd_ = 0.f;
#pragma unroll
      for (int e = 0; e < 10; ++e) su_ += svT[k * 20 + e];
#pragma unroll
      for (int e = 10; e < 20; ++e) sd_ += svT[k * 20 + e];
      mu[k] = su_ * 0.1f;
      md[k] = sd_ * 0.1f;
    }
#pragma unroll
    for (int t5 = 0; t5 < 5; ++t5) {
      int t = tid + 256 * t5;
      int half = t / 640, rem = t % 640, j = rem >> 5, c = rem & 31;
      float s = 0.f;
      for (int i = half * 10; i < half * 10 + 10; ++i) s += pvbuf[(i * 20 + j) * 32 + c];
      (half ? pdT : puT)[c * 20 + j] = s * 0.1f;
    }
    __syncthreads();
    if (l == 3) break;

    const float* W = s_w + l * 832 * 256;
    const float* PW = p_w + l * 1024;

    // ---- single stream: thread j computes column j for all 20 electrons ----
    const int j = tid;
    float sacc[20];
    {
      float accm = s_b[l * 256 + j];
#pragma unroll 4
      for (int k = 0; k < 256; ++k)
        accm += mu[k] * W[(256 + k) * 256 + j] + md[k] * W[(512 + k) * 256 + j];
#pragma unroll
      for (int e = 0; e < 20; ++e) sacc[e] = accm;
#pragma unroll 2
      for (int k = 0; k < 256; ++k) {
        float wk = W[k * 256 + j];
        const float* row = &svT[k * 20];
#pragma unroll
        for (int e = 0; e < 20; ++e) sacc[e] += row[e] * wk;
      }
#pragma unroll 2
      for (int c = 0; c < 32; ++c) {
        float wuc = W[(768 + c) * 256 + j], wdc = W[(800 + c) * 256 + j];
        const float* ru_ = &puT[c * 20];
        const float* rd_ = &pdT[c * 20];
#pragma unroll
        for (int e = 0; e < 20; ++e) sacc[e] += ru_[e] * wuc + rd_[e] * wdc;
      }
#pragma unroll
      for (int e = 0; e < 20; ++e) sacc[e] = tanhf(sacc[e]);
    }
    __syncthreads();
#pragma unroll
    for (int e = 0; e < 20; ++e) svT[j * 20 + e] += sacc[e];  // residual

    // ---- pair stream: channel c = tid&31 constant; weights in registers ----
    {
      const int c = tid & 31;
      float pwc[32];
#pragma unroll
      for (int k = 0; k < 32; ++k) pwc[k] = PW[k * 32 + c];
      const float pbc = p_b[l * 32 + c];
      float pacc[25];
      // group A: rows i<10 (o < 6400)
#pragma unroll
      for (int s = 0; s < 25; ++s) {
        int o = tid + 256 * s;
        const float* row = &pvbuf[o & ~31];
        float acc = pbc;
#pragma unroll
        for (int k = 0; k < 32; ++k) acc += row[k] * pwc[k];
        pacc[s] = tanhf(acc);
      }
      __syncthreads();
#pragma unroll
      for (int s = 0; s < 25; ++s) pvbuf[tid + 256 * s] += pacc[s];
      // group B: rows i>=10 (disjoint from A's writes)
#pragma unroll
      for (int s = 25; s < 50; ++s) {
        int o = tid + 256 * s;
        const float* row = &pvbuf[o & ~31];
        float acc = pbc;
#pragma unroll
        for (int k = 0; k < 32; ++k) acc += row[k] * pwc[k];
        pacc[s - 25] = tanhf(acc);
      }
      __syncthreads();
#pragma unroll
      for (int s = 25; s < 50; ++s) pvbuf[tid + 256 * s] += pacc[s - 25];
    }
    __syncthreads();
  }

  // ---- vu/vd heads: s_u/s_d into reused pvbuf (pv no longer needed) ----
  float* suT = pvbuf;              // [256][12] padded rows
  float* sdT = pvbuf + 256 * 12;
  float* orb = pvbuf + 2 * 256 * 12;  // [32][100]
#pragma unroll
  for (int s = 0; s < 2; ++s) {
    const float* W = s ? vd_w : vu_w;
    const float* Bv = s ? vd_b : vu_b;
    float* dst = s ? sdT : suT;
    const int e0 = s * 10;
    const int j = tid;
    float accm = Bv[j];
#pragma unroll 4
    for (int k = 0; k < 256; ++k)
      accm += mu[k] * W[(256 + k) * 256 + j] + md[k] * W[(512 + k) * 256 + j];
    float acc[10];
#pragma unroll
    for (int e = 0; e < 10; ++e) acc[e] = accm;
#pragma unroll 2
    for (int k = 0; k < 256; ++k) {
      float wk = W[k * 256 + j];
      const float* row = &svT[k * 20 + e0];
#pragma unroll
      for (int e = 0; e < 10; ++e) acc[e] += row[e] * wk;
    }
#pragma unroll 2
    for (int c = 0; c < 32; ++c) {
      float wuc = W[(768 + c) * 256 + j], wdc = W[(800 + c) * 256 + j];
#pragma unroll
      for (int e = 0; e < 10; ++e)
        acc[e] += puT[c * 20 + e0 + e] * wuc + pdT[c * 20 + e0 + e] * wdc;
    }
#pragma unroll
    for (int e = 0; e < 10; ++e) dst[j * 12 + e] = tanhf(acc[e]);
  }
  __syncthreads();

  // ---- orbital matrices: w_u/w_d + envelope scaling ----
  for (int t = tid; t < 320; t += 256) {
    const int mat = t / 160, col = t % 160;
    const float* W = mat ? wd_w : wu_w;
    const float* Bv = mat ? wd_b : wu_b;
    const float* src = mat ? sdT : suT;
    float acc[10];
    const float bb = Bv[col];
#pragma unroll
    for (int e = 0; e < 10; ++e) acc[e] = bb;
#pragma unroll 2
    for (int k = 0; k < 256; ++k) {
      float wk = W[k * 160 + col];
      const float* row = &src[k * 12];
#pragma unroll
      for (int e = 0; e < 10; ++e) acc[e] += row[e] * wk;
    }
    const int d = col / 10, jo = col % 10;
#pragma unroll
    for (int e = 0; e < 10; ++e)
      orb[(mat * 16 + d) * 100 + e * 10 + jo] = acc[e] * expv[mat * 10 + e];
  }
  __syncthreads();

  // ---- slogdet: one 10x10 partial-pivot LU per thread (tid<32) ----
  if (tid < 32) {
    float* M = orb + tid * 100;
    float ldet = 0.f, sg = 1.f;
    for (int c = 0; c < 10; ++c) {
      int p = c;
      float mx = fabsf(M[c * 10 + c]);
      for (int rr = c + 1; rr < 10; ++rr) {
        float v = fabsf(M[rr * 10 + c]);
        if (v > mx) { mx = v; p = rr; }
      }
      if (p != c) {
        sg = -sg;
        for (int cc = c; cc < 10; ++cc) {
          float tmp = M[c * 10 + cc];
          M[c * 10 + cc] = M[p * 10 + cc];
          M[p * 10 + cc] = tmp;
        }
      }
      float piv = M[c * 10 + c];
      if (piv < 0.f) sg = -sg;
      ldet += logf(fabsf(piv));
      float inv = 1.f / piv;
      for (int rr = c + 1; rr < 10; ++rr) {
        float f = M[rr * 10 + c] * inv;
        for (int cc = c + 1; cc < 10; ++cc) M[rr * 10 + cc] -= f * M[c * 10 + cc];
      }
    }
    lu_s[tid] = ldet;
    sg_s[tid] = sg;
  }
  __syncthreads();

  // ---- combine dets ----
  if (tid == 0) {
    float mx = -1e30f;
    float l[16], sgn[16];
#pragma unroll
    for (int d = 0; d < 16; ++d) {
      l[d] = lu_s[d] + lu_s[16 + d];
      sgn[d] = sg_s[d] * sg_s[16 + d];
      mx = fmaxf(mx, l[d]);
    }
    float psi = 0.f;
#pragma unroll
    for (int d = 0; d < 16; ++d) psi += sgn[d] * expf(l[d] - mx) * wf_w[d];
    out[b] = logf(fabsf(psi)) + mx;
  }
}

}  // namespace

extern "C" void kernel_launch(void* const* d_in, const int* in_sizes, int n_in,
                              void* d_out, int out_size, void* d_ws, size_t ws_size,
                              hipStream_t stream) {
  const float* r = (const float*)d_in[0];
  const float* a = (const float*)d_in[1];
  const float* s_w0 = (const float*)d_in[2];
  const float* s_b0 = (const float*)d_in[3];
  const float* s_w = (const float*)d_in[4];
  const float* s_b = (const float*)d_in[5];
  const float* p_w0 = (const float*)d_in[6];
  const float* p_b0 = (const float*)d_in[7];
  const float* p_w = (const float*)d_in[8];
  const float* p_b = (const float*)d_in[9];
  const float* vu_w = (const float*)d_in[10];
  const float* vu_b = (const float*)d_in[11];
  const float* vd_w = (const float*)d_in[12];
  const float* vd_b = (const float*)d_in[13];
  const float* wu_w = (const float*)d_in[14];
  const float* wu_b = (const float*)d_in[15];
  const float* wd_w = (const float*)d_in[16];
  const float* wd_b = (const float*)d_in[17];
  const float* wf_w = (const float*)d_in[18];

  const int nb = in_sizes[0] / 60;  // [B,20,3]
  ansatz_fused<<<dim3(nb), dim3(256), 0, stream>>>(
      r, a, s_w0, s_b0, s_w, s_b, p_w0, p_b0, p_w, p_b,
      vu_w, vu_b, vd_w, vd_b, wu_w, wu_b, wd_w, wd_b, wf_w,
      (float*)d_out);
}